// Round 5
// baseline (603.762 us; speedup 1.0000x reference)
//
#include <hip/hip_runtime.h>
#include <hip/hip_bf16.h>
#include <stdint.h>

#define NEXP 16
#define KSEL 4
#define HDIM 2048
#define IDIM 1024
#define TTOK 2048
#define MAXTILES 80
#define NT1 16            // gemm1 n-tiles (IDIM/64)
#define NT2 32            // gemm2 n-tiles (HDIM/64)
#define MAXB1 (MAXTILES * NT1)   // 1280, divisible by 8
#define MAXB2 (MAXTILES * NT2)   // 2560, divisible by 8

typedef __attribute__((ext_vector_type(8))) short bf16x8;
typedef __attribute__((ext_vector_type(4))) float f32x4;

__device__ __forceinline__ uint32_t pack2(float a, float b) {
  __hip_bfloat162 h = __float22bfloat162_rn(float2{a, b});
  uint32_t u;
  __builtin_memcpy(&u, &h, 4);
  return u;
}
__device__ __forceinline__ ushort bf1(float a) {
  __hip_bfloat16 h = __float2bfloat16(a);
  ushort u;
  __builtin_memcpy(&u, &h, 2);
  return u;
}
// LDS tiles are [rows][32 bf16] (64B rows). XOR-swizzle the 16B-chunk
// position with row bits: frag reads and staged writes both land 2-way per
// bank group (free, m136). Verified 0 conflicts in R3/R4.
__device__ __forceinline__ int swz32(int row, int ecol) {
  return row * 32 + (ecol ^ (((row >> 1) & 3) << 3));
}

// T4 barrier: drain own LDS ops (cross-wave write->read handoff), then raw
// barrier. Crucially does NOT drain vmcnt -> global prefetch loads stay in
// flight across the barrier (the m97-structure ~20% stall killer).
__device__ __forceinline__ void lds_barrier() {
  asm volatile("s_waitcnt lgkmcnt(0)" ::: "memory");
  __builtin_amdgcn_s_barrier();
}

// ---------------- router: logits, top-4, softmax, x->bf16 ----------------
__global__ __launch_bounds__(256) void router_kernel(
    const float* __restrict__ x, const float* __restrict__ gw,
    ushort* __restrict__ xb, int* __restrict__ topk_id,
    float* __restrict__ topk_w, int* __restrict__ counts)
{
  const int wid = threadIdx.x >> 6;
  const int lane = threadIdx.x & 63;
  const int t = blockIdx.x * 4 + wid;
  const float4* x4 = (const float4*)(x + (size_t)t * HDIM);
  const float4* gw4 = (const float4*)gw;
  float acc[NEXP];
#pragma unroll
  for (int e = 0; e < NEXP; ++e) acc[e] = 0.f;
#pragma unroll
  for (int i = 0; i < HDIM / 256; ++i) {
    const int idx = i * 64 + lane;
    float4 xv = x4[idx];
    uint2 xp;
    xp.x = pack2(xv.x, xv.y);
    xp.y = pack2(xv.z, xv.w);
    *(uint2*)(xb + (size_t)t * HDIM + idx * 4) = xp;
#pragma unroll
    for (int e = 0; e < NEXP; ++e) {
      float4 wv = gw4[e * (HDIM / 4) + idx];
      acc[e] += xv.x * wv.x + xv.y * wv.y + xv.z * wv.z + xv.w * wv.w;
    }
  }
#pragma unroll
  for (int e = 0; e < NEXP; ++e) {
#pragma unroll
    for (int off = 32; off >= 1; off >>= 1)
      acc[e] += __shfl_xor(acc[e], off);
  }
  if (lane == 0) {
    unsigned taken = 0;
    float vals[KSEL];
    int ids[KSEL];
#pragma unroll
    for (int k = 0; k < KSEL; ++k) {
      float bv = -3.4e38f; int bi = 0;
      for (int e = 0; e < NEXP; ++e)
        if (!((taken >> e) & 1u) && acc[e] > bv) { bv = acc[e]; bi = e; }
      taken |= 1u << bi; vals[k] = bv; ids[k] = bi;
    }
    float m = vals[0], s = 0.f, w[KSEL];
#pragma unroll
    for (int k = 0; k < KSEL; ++k) { w[k] = __expf(vals[k] - m); s += w[k]; }
    float is = 1.f / s;
#pragma unroll
    for (int k = 0; k < KSEL; ++k) {
      topk_id[t * KSEL + k] = ids[k];
      topk_w[t * KSEL + k] = w[k] * is;
      atomicAdd(&counts[ids[k]], 1);
    }
  }
}

// ------ plan: offsets + 1D work lists, (e, nt-major, mt-inner) order ------
__global__ void plan_kernel(const int* __restrict__ counts, int* __restrict__ offsets,
                            int* __restrict__ nW1, int* __restrict__ nW2,
                            int* __restrict__ wl1, int* __restrict__ wl2) {
  __shared__ int tiles[NEXP], pre[NEXP];
  const int tid = threadIdx.x;
  if (tid == 0) {
    int s = 0, p = 0;
    for (int e = 0; e < NEXP; ++e) {
      offsets[e] = s; s += counts[e];
      tiles[e] = (counts[e] + 127) >> 7;
      pre[e] = p; p += tiles[e];
    }
    offsets[NEXP] = s;
    *nW1 = p * NT1;
    *nW2 = p * NT2;
  }
  __syncthreads();
  if (tid < NEXP) {
    const int e = tid, T = tiles[e];
    int idx = pre[e] * NT1;
    for (int nt = 0; nt < NT1; ++nt)
      for (int mt = 0; mt < T; ++mt)
        wl1[idx++] = (e << 12) | (nt << 6) | mt;
  } else if (tid < 2 * NEXP) {
    const int e = tid - NEXP, T = tiles[e];
    int idx = pre[e] * NT2;
    for (int nt = 0; nt < NT2; ++nt)
      for (int mt = 0; mt < T; ++mt)
        wl2[idx++] = (e << 12) | (nt << 6) | mt;
  }
}

// ---------------- scatter: bucket tokens by expert ----------------
__global__ __launch_bounds__(256) void scatter_kernel(
    const int* __restrict__ topk_id, const int* __restrict__ offsets,
    int* __restrict__ cursors, int* __restrict__ rowTok, int* __restrict__ inv)
{
  const int t = blockIdx.x * 256 + threadIdx.x;
  if (t >= TTOK) return;
#pragma unroll
  for (int k = 0; k < KSEL; ++k) {
    const int e = topk_id[t * KSEL + k];
    const int pos = atomicAdd(&cursors[e], 1);
    const int row = offsets[e] + pos;
    rowTok[row] = t;
    inv[t * KSEL + k] = row;
  }
}

// -------- GEMM1: h = silu(x.w1g^T) * (x.w1u^T). BM=128 BN=64 BK=32 --------
__global__ __launch_bounds__(256, 4) void gemm1_kernel(
    const ushort* __restrict__ xb, const float* __restrict__ w1g,
    const float* __restrict__ w1u, const int* __restrict__ rowTok,
    const int* __restrict__ counts, const int* __restrict__ offsets,
    const int* __restrict__ nW1, const int* __restrict__ wl1,
    ushort* __restrict__ hbuf)
{
  const int nTot = *nW1;
  // XCD-chunked bijection: consecutive logical L (mt-siblings sharing a
  // weight panel) land on the same XCD -> panel re-reads hit that XCD's L2.
  const int L = (blockIdx.x & 7) * (MAXB1 / 8) + (blockIdx.x >> 3);
  if (L >= nTot) return;
  const int w = wl1[L];
  const int e = w >> 12, nt = (w >> 6) & 63, mt = w & 63;
  const int n_e = counts[e], rowbase = offsets[e];

  __shared__ ushort As[2][128 * 32];
  __shared__ ushort Bg[2][64 * 32];
  __shared__ ushort Bu[2][64 * 32];

  const int tid = threadIdx.x;
  const int sr = tid >> 2;           // row 0..63
  const int sc = (tid & 3) << 3;     // elem col base 0/8/16/24
  const int r0 = mt * 128 + sr;
  const int r1 = r0 + 64;
  const int tok0 = rowTok[rowbase + (r0 < n_e ? r0 : n_e - 1)];
  const int tok1 = rowTok[rowbase + (r1 < n_e ? r1 : n_e - 1)];
  const ushort* aS0 = xb + (size_t)tok0 * HDIM + sc;
  const ushort* aS1 = xb + (size_t)tok1 * HDIM + sc;
  const float* gS = w1g + (size_t)e * IDIM * HDIM + (size_t)(nt * 64 + sr) * HDIM + sc;
  const float* uS = w1u + (size_t)e * IDIM * HDIM + (size_t)(nt * 64 + sr) * HDIM + sc;

  uint4 aR0, aR1;
  float4 gL, gH, uL, uH;

  auto LOAD = [&](int kt) {
    const int k0 = kt * 32;
    aR0 = *(const uint4*)(aS0 + k0);
    aR1 = *(const uint4*)(aS1 + k0);
    gL = *(const float4*)(gS + k0);
    gH = *(const float4*)(gS + k0 + 4);
    uL = *(const float4*)(uS + k0);
    uH = *(const float4*)(uS + k0 + 4);
  };
  auto STORE = [&](int b) {
    *(uint4*)&As[b][swz32(sr, sc)] = aR0;
    *(uint4*)&As[b][swz32(sr + 64, sc)] = aR1;
    uint4 t0;
    t0.x = pack2(gL.x, gL.y); t0.y = pack2(gL.z, gL.w);
    t0.z = pack2(gH.x, gH.y); t0.w = pack2(gH.z, gH.w);
    *(uint4*)&Bg[b][swz32(sr, sc)] = t0;
    t0.x = pack2(uL.x, uL.y); t0.y = pack2(uL.z, uL.w);
    t0.z = pack2(uH.x, uH.y); t0.w = pack2(uH.z, uH.w);
    *(uint4*)&Bu[b][swz32(sr, sc)] = t0;
  };

  const int lane = tid & 63;
  const int wid = tid >> 6;
  const int wr = (wid >> 1) << 6;   // wave row 0/64
  const int wc = (wid & 1) << 5;    // wave col 0/32
  const int lr = lane & 15;
  const int lk = (lane >> 4) << 3;

  f32x4 accG[4][2], accU[4][2];
#pragma unroll
  for (int i = 0; i < 4; ++i)
#pragma unroll
    for (int j = 0; j < 2; ++j) {
      accG[i][j] = (f32x4){0.f, 0.f, 0.f, 0.f};
      accU[i][j] = (f32x4){0.f, 0.f, 0.f, 0.f};
    }

  const int NT = HDIM / 32;  // 64
  LOAD(0);
  STORE(0);
  LOAD(1);
  lds_barrier();

  for (int kt = 0; kt < NT; ++kt) {
    const int cur = kt & 1;

    bf16x8 af[4], bgf[2], buf_[2];
#pragma unroll
    for (int mi = 0; mi < 4; ++mi)
      af[mi] = *(const bf16x8*)&As[cur][swz32(wr + mi * 16 + lr, lk)];
#pragma unroll
    for (int ni = 0; ni < 2; ++ni) {
      bgf[ni] = *(const bf16x8*)&Bg[cur][swz32(wc + ni * 16 + lr, lk)];
      buf_[ni] = *(const bf16x8*)&Bu[cur][swz32(wc + ni * 16 + lr, lk)];
    }

    if (kt + 1 < NT) STORE(cur ^ 1);   // compiler emits counted vmcnt here
    if (kt + 2 < NT) LOAD(kt + 2);     // stays in flight across the barrier

    lds_barrier();                      // no vmcnt drain (T4)

    __builtin_amdgcn_s_setprio(1);      // T5: waves now role-split
#pragma unroll
    for (int mi = 0; mi < 4; ++mi)
#pragma unroll
      for (int ni = 0; ni < 2; ++ni) {
        accG[mi][ni] = __builtin_amdgcn_mfma_f32_16x16x32_bf16(af[mi], bgf[ni], accG[mi][ni], 0, 0, 0);
        accU[mi][ni] = __builtin_amdgcn_mfma_f32_16x16x32_bf16(af[mi], buf_[ni], accU[mi][ni], 0, 0, 0);
      }
    __builtin_amdgcn_s_setprio(0);
  }

#pragma unroll
  for (int mi = 0; mi < 4; ++mi) {
#pragma unroll
    for (int ni = 0; ni < 2; ++ni) {
      const int col = nt * 64 + wc + ni * 16 + lr;
#pragma unroll
      for (int r = 0; r < 4; ++r) {
        const int mrow = mt * 128 + wr + mi * 16 + ((lane >> 4) << 2) + r;
        if (mrow < n_e) {
          const float gv = accG[mi][ni][r];
          const float uv = accU[mi][ni][r];
          const float hv = (gv / (1.f + __expf(-gv))) * uv;
          hbuf[(size_t)(rowbase + mrow) * IDIM + col] = bf1(hv);
        }
      }
    }
  }
}

// -------- GEMM2: po = h . w2^T (per expert). BM=128 BN=64 BK=32 -----------
__global__ __launch_bounds__(256, 4) void gemm2_kernel(
    const ushort* __restrict__ hbuf, const float* __restrict__ w2,
    const int* __restrict__ counts, const int* __restrict__ offsets,
    const int* __restrict__ nW2, const int* __restrict__ wl2,
    ushort* __restrict__ po)
{
  const int nTot = *nW2;
  const int L = (blockIdx.x & 7) * (MAXB2 / 8) + (blockIdx.x >> 3);
  if (L >= nTot) return;
  const int w = wl2[L];
  const int e = w >> 12, nt = (w >> 6) & 63, mt = w & 63;
  const int n_e = counts[e], rowbase = offsets[e];

  __shared__ ushort As[2][128 * 32];
  __shared__ ushort Bs[2][64 * 32];

  const int tid = threadIdx.x;
  const int sr = tid >> 2;
  const int sc = (tid & 3) << 3;
  const int r0 = mt * 128 + sr;
  const int r1 = r0 + 64;
  const int g0 = rowbase + (r0 < n_e ? r0 : n_e - 1);
  const int g1 = rowbase + (r1 < n_e ? r1 : n_e - 1);
  const ushort* aS0 = hbuf + (size_t)g0 * IDIM + sc;
  const ushort* aS1 = hbuf + (size_t)g1 * IDIM + sc;
  const float* bS = w2 + (size_t)e * HDIM * IDIM + (size_t)(nt * 64 + sr) * IDIM + sc;

  uint4 aR0, aR1;
  float4 bL, bH;

  auto LOAD = [&](int kt) {
    const int k0 = kt * 32;
    aR0 = *(const uint4*)(aS0 + k0);
    aR1 = *(const uint4*)(aS1 + k0);
    bL = *(const float4*)(bS + k0);
    bH = *(const float4*)(bS + k0 + 4);
  };
  auto STORE = [&](int b) {
    *(uint4*)&As[b][swz32(sr, sc)] = aR0;
    *(uint4*)&As[b][swz32(sr + 64, sc)] = aR1;
    uint4 t0;
    t0.x = pack2(bL.x, bL.y); t0.y = pack2(bL.z, bL.w);
    t0.z = pack2(bH.x, bH.y); t0.w = pack2(bH.z, bH.w);
    *(uint4*)&Bs[b][swz32(sr, sc)] = t0;
  };

  const int lane = tid & 63;
  const int wid = tid >> 6;
  const int wr = (wid >> 1) << 6;
  const int wc = (wid & 1) << 5;
  const int lr = lane & 15;
  const int lk = (lane >> 4) << 3;

  f32x4 acc[4][2];
#pragma unroll
  for (int i = 0; i < 4; ++i)
#pragma unroll
    for (int j = 0; j < 2; ++j) acc[i][j] = (f32x4){0.f, 0.f, 0.f, 0.f};

  const int NT = IDIM / 32;  // 32
  LOAD(0);
  STORE(0);
  LOAD(1);
  lds_barrier();

  for (int kt = 0; kt < NT; ++kt) {
    const int cur = kt & 1;

    bf16x8 af[4], bf[2];
#pragma unroll
    for (int mi = 0; mi < 4; ++mi)
      af[mi] = *(const bf16x8*)&As[cur][swz32(wr + mi * 16 + lr, lk)];
#pragma unroll
    for (int ni = 0; ni < 2; ++ni)
      bf[ni] = *(const bf16x8*)&Bs[cur][swz32(wc + ni * 16 + lr, lk)];

    if (kt + 1 < NT) STORE(cur ^ 1);
    if (kt + 2 < NT) LOAD(kt + 2);

    lds_barrier();

    __builtin_amdgcn_s_setprio(1);
#pragma unroll
    for (int mi = 0; mi < 4; ++mi)
#pragma unroll
      for (int ni = 0; ni < 2; ++ni)
        acc[mi][ni] = __builtin_amdgcn_mfma_f32_16x16x32_bf16(af[mi], bf[ni], acc[mi][ni], 0, 0, 0);
    __builtin_amdgcn_s_setprio(0);
  }

#pragma unroll
  for (int mi = 0; mi < 4; ++mi) {
#pragma unroll
    for (int ni = 0; ni < 2; ++ni) {
      const int col = nt * 64 + wc + ni * 16 + lr;
#pragma unroll
      for (int r = 0; r < 4; ++r) {
        const int mrow = mt * 128 + wr + mi * 16 + ((lane >> 4) << 2) + r;
        if (mrow < n_e)
          po[(size_t)(rowbase + mrow) * HDIM + col] = bf1(acc[mi][ni][r]);
      }
    }
  }
}

// ---------------- combine: out[t] = sum_k w_k * po[row_k] -----------------
__global__ __launch_bounds__(256) void combine_kernel(
    const ushort* __restrict__ po, const int* __restrict__ inv,
    const float* __restrict__ tw, float* __restrict__ out)
{
  const int t = blockIdx.x;
  const int r0 = inv[t * 4 + 0], r1 = inv[t * 4 + 1];
  const int r2 = inv[t * 4 + 2], r3 = inv[t * 4 + 3];
  const float w0 = tw[t * 4 + 0], w1 = tw[t * 4 + 1];
  const float w2v = tw[t * 4 + 2], w3 = tw[t * 4 + 3];
  const int i = threadIdx.x;  // HDIM/8 == 256 lanes, 8 elems each
  uint4 v0 = *(const uint4*)(po + (size_t)r0 * HDIM + i * 8);
  uint4 v1 = *(const uint4*)(po + (size_t)r1 * HDIM + i * 8);
  uint4 v2 = *(const uint4*)(po + (size_t)r2 * HDIM + i * 8);
  uint4 v3 = *(const uint4*)(po + (size_t)r3 * HDIM + i * 8);
  float o[8];
#pragma unroll
  for (int w = 0; w < 4; ++w) {
    const uint32_t a = (&v0.x)[w], b = (&v1.x)[w], c = (&v2.x)[w], d = (&v3.x)[w];
    o[w * 2 + 0] = w0 * __builtin_bit_cast(float, a << 16) +
                   w1 * __builtin_bit_cast(float, b << 16) +
                   w2v * __builtin_bit_cast(float, c << 16) +
                   w3 * __builtin_bit_cast(float, d << 16);
    o[w * 2 + 1] = w0 * __builtin_bit_cast(float, a & 0xffff0000u) +
                   w1 * __builtin_bit_cast(float, b & 0xffff0000u) +
                   w2v * __builtin_bit_cast(float, c & 0xffff0000u) +
                   w3 * __builtin_bit_cast(float, d & 0xffff0000u);
  }
  float4* o4 = (float4*)(out + (size_t)t * HDIM + i * 8);
  o4[0] = (float4){o[0], o[1], o[2], o[3]};
  o4[1] = (float4){o[4], o[5], o[6], o[7]};
}

extern "C" void kernel_launch(void* const* d_in, const int* in_sizes, int n_in,
                              void* d_out, int out_size, void* d_ws, size_t ws_size,
                              hipStream_t stream) {
  const float* x   = (const float*)d_in[0];
  const float* gw  = (const float*)d_in[1];
  const float* w1g = (const float*)d_in[2];
  const float* w1u = (const float*)d_in[3];
  const float* w2  = (const float*)d_in[4];
  float* out = (float*)d_out;

  char* ws = (char*)d_ws;
  ushort* xb     = (ushort*)(ws + 0);
  ushort* hbuf   = (ushort*)(ws + 8388608);
  ushort* po     = (ushort*)(ws + 25165824);
  int*    tkid   = (int*)   (ws + 58720256);
  float*  tkw    = (float*) (ws + 58753024);
  int*    rowTok = (int*)   (ws + 58785792);
  int*    inv    = (int*)   (ws + 58818560);
  int*    ctrl   = (int*)   (ws + 58851328);
  int* counts  = ctrl;          // 16
  int* cursors = ctrl + 16;     // 16
  int* offsets = ctrl + 32;     // 17
  int* nW1     = ctrl + 50;     // 1
  int* nW2     = ctrl + 51;     // 1
  int* wl1     = ctrl + 64;     // MAXB1 (1280)
  int* wl2     = ctrl + 64 + MAXB1;  // MAXB2 (2560)

  (void)hipMemsetAsync(ctrl, 0, 256, stream);
  router_kernel<<<TTOK / 4, 256, 0, stream>>>(x, gw, xb, tkid, tkw, counts);
  plan_kernel<<<1, 64, 0, stream>>>(counts, offsets, nW1, nW2, wl1, wl2);
  scatter_kernel<<<TTOK / 256, 256, 0, stream>>>(tkid, offsets, cursors, rowTok, inv);
  gemm1_kernel<<<MAXB1, 256, 0, stream>>>(xb, w1g, w1u, rowTok, counts, offsets,
                                          nW1, wl1, hbuf);
  gemm2_kernel<<<MAXB2, 256, 0, stream>>>(hbuf, w2, counts, offsets,
                                          nW2, wl2, po);
  combine_kernel<<<TTOK, 256, 0, stream>>>(po, inv, tkw, out);
}

// Round 6
// 494.943 us; speedup vs baseline: 1.2199x; 1.2199x over previous
//
#include <hip/hip_runtime.h>
#include <hip/hip_bf16.h>
#include <stdint.h>

#define NEXP 16
#define KSEL 4
#define HDIM 2048
#define IDIM 1024
#define TTOK 2048
#define MAXTILES 80
#define NT1 16            // gemm1 n-tiles (IDIM/64)
#define NT2 32            // gemm2 n-tiles (HDIM/64)
#define MAXB1 (MAXTILES * NT1)   // 1280
#define MAXB2 (MAXTILES * NT2)   // 2560

typedef __attribute__((ext_vector_type(8))) short bf16x8;
typedef __attribute__((ext_vector_type(4))) float f32x4;

__device__ __forceinline__ uint32_t pack2(float a, float b) {
  __hip_bfloat162 h = __float22bfloat162_rn(float2{a, b});
  uint32_t u;
  __builtin_memcpy(&u, &h, 4);
  return u;
}
__device__ __forceinline__ ushort bf1(float a) {
  __hip_bfloat16 h = __float2bfloat16(a);
  ushort u;
  __builtin_memcpy(&u, &h, 2);
  return u;
}
// XOR-swizzled [rows][32 bf16] LDS layout; 0 bank conflicts verified R3/R4.
__device__ __forceinline__ int swz32(int row, int ecol) {
  return row * 32 + (ecol ^ (((row >> 1) & 3) << 3));
}

// T4 barrier: drain own LDS ops only; global loads stay in flight.
__device__ __forceinline__ void lds_barrier() {
  asm volatile("s_waitcnt lgkmcnt(0)\n\ts_barrier" ::: "memory");
}

// ---------------- router: logits, top-4, softmax, x->bf16 ----------------
__global__ __launch_bounds__(256) void router_kernel(
    const float* __restrict__ x, const float* __restrict__ gw,
    ushort* __restrict__ xb, int* __restrict__ topk_id,
    float* __restrict__ topk_w, int* __restrict__ counts)
{
  const int wid = threadIdx.x >> 6;
  const int lane = threadIdx.x & 63;
  const int t = blockIdx.x * 4 + wid;
  const float4* x4 = (const float4*)(x + (size_t)t * HDIM);
  const float4* gw4 = (const float4*)gw;
  float acc[NEXP];
#pragma unroll
  for (int e = 0; e < NEXP; ++e) acc[e] = 0.f;
#pragma unroll
  for (int i = 0; i < HDIM / 256; ++i) {
    const int idx = i * 64 + lane;
    float4 xv = x4[idx];
    uint2 xp;
    xp.x = pack2(xv.x, xv.y);
    xp.y = pack2(xv.z, xv.w);
    *(uint2*)(xb + (size_t)t * HDIM + idx * 4) = xp;
#pragma unroll
    for (int e = 0; e < NEXP; ++e) {
      float4 wv = gw4[e * (HDIM / 4) + idx];
      acc[e] += xv.x * wv.x + xv.y * wv.y + xv.z * wv.z + xv.w * wv.w;
    }
  }
#pragma unroll
  for (int e = 0; e < NEXP; ++e) {
#pragma unroll
    for (int off = 32; off >= 1; off >>= 1)
      acc[e] += __shfl_xor(acc[e], off);
  }
  if (lane == 0) {
    unsigned taken = 0;
    float vals[KSEL];
    int ids[KSEL];
#pragma unroll
    for (int k = 0; k < KSEL; ++k) {
      float bv = -3.4e38f; int bi = 0;
      for (int e = 0; e < NEXP; ++e)
        if (!((taken >> e) & 1u) && acc[e] > bv) { bv = acc[e]; bi = e; }
      taken |= 1u << bi; vals[k] = bv; ids[k] = bi;
    }
    float m = vals[0], s = 0.f, w[KSEL];
#pragma unroll
    for (int k = 0; k < KSEL; ++k) { w[k] = __expf(vals[k] - m); s += w[k]; }
    float is = 1.f / s;
#pragma unroll
    for (int k = 0; k < KSEL; ++k) {
      topk_id[t * KSEL + k] = ids[k];
      topk_w[t * KSEL + k] = w[k] * is;
      atomicAdd(&counts[ids[k]], 1);
    }
  }
}

// ------ plan: offsets + 1D work lists, (e, nt-major, mt-inner) order ------
__global__ void plan_kernel(const int* __restrict__ counts, int* __restrict__ offsets,
                            int* __restrict__ nW1, int* __restrict__ nW2,
                            int* __restrict__ wl1, int* __restrict__ wl2) {
  __shared__ int tiles[NEXP], pre[NEXP];
  const int tid = threadIdx.x;
  if (tid == 0) {
    int s = 0, p = 0;
    for (int e = 0; e < NEXP; ++e) {
      offsets[e] = s; s += counts[e];
      tiles[e] = (counts[e] + 127) >> 7;
      pre[e] = p; p += tiles[e];
    }
    offsets[NEXP] = s;
    *nW1 = p * NT1;
    *nW2 = p * NT2;
  }
  __syncthreads();
  if (tid < NEXP) {
    const int e = tid, T = tiles[e];
    int idx = pre[e] * NT1;
    for (int nt = 0; nt < NT1; ++nt)
      for (int mt = 0; mt < T; ++mt)
        wl1[idx++] = (e << 12) | (nt << 6) | mt;
  } else if (tid < 2 * NEXP) {
    const int e = tid - NEXP, T = tiles[e];
    int idx = pre[e] * NT2;
    for (int nt = 0; nt < NT2; ++nt)
      for (int mt = 0; mt < T; ++mt)
        wl2[idx++] = (e << 12) | (nt << 6) | mt;
  }
}

// ---------------- scatter: bucket tokens by expert ----------------
__global__ __launch_bounds__(256) void scatter_kernel(
    const int* __restrict__ topk_id, const int* __restrict__ offsets,
    int* __restrict__ cursors, int* __restrict__ rowTok, int* __restrict__ inv)
{
  const int t = blockIdx.x * 256 + threadIdx.x;
  if (t >= TTOK) return;
#pragma unroll
  for (int k = 0; k < KSEL; ++k) {
    const int e = topk_id[t * KSEL + k];
    const int pos = atomicAdd(&cursors[e], 1);
    const int row = offsets[e] + pos;
    rowTok[row] = t;
    inv[t * KSEL + k] = row;
  }
}

// -------- GEMM1: h = silu(x.w1g^T) * (x.w1u^T). BM=128 BN=64 BK=32 --------
// K-loop unrolled x2 with two named staging register sets (X/Y): each
// ds_write waits (compiler counted-vmcnt) only on loads issued 2 sub-iters
// (~500 cyc) earlier; barrier never drains vmcnt (T4).
__global__ __launch_bounds__(256, 2) void gemm1_kernel(
    const ushort* __restrict__ xb, const float* __restrict__ w1g,
    const float* __restrict__ w1u, const int* __restrict__ rowTok,
    const int* __restrict__ counts, const int* __restrict__ offsets,
    const int* __restrict__ nW1, const int* __restrict__ wl1,
    ushort* __restrict__ hbuf)
{
  const int nTot = *nW1;
  const int L = (blockIdx.x & 7) * (MAXB1 / 8) + (blockIdx.x >> 3);
  if (L >= nTot) return;
  const int w = wl1[L];
  const int e = w >> 12, nt = (w >> 6) & 63, mt = w & 63;
  const int n_e = counts[e], rowbase = offsets[e];

  __shared__ ushort As[2][128 * 32];
  __shared__ ushort Bg[2][64 * 32];
  __shared__ ushort Bu[2][64 * 32];

  const int tid = threadIdx.x;
  const int sr = tid >> 2;           // row 0..63
  const int sc = (tid & 3) << 3;     // elem col base 0/8/16/24
  const int r0 = mt * 128 + sr;
  const int r1 = r0 + 64;
  const int tok0 = rowTok[rowbase + (r0 < n_e ? r0 : n_e - 1)];
  const int tok1 = rowTok[rowbase + (r1 < n_e ? r1 : n_e - 1)];
  const ushort* aS0 = xb + (size_t)tok0 * HDIM + sc;
  const ushort* aS1 = xb + (size_t)tok1 * HDIM + sc;
  const float* gS = w1g + (size_t)e * IDIM * HDIM + (size_t)(nt * 64 + sr) * HDIM + sc;
  const float* uS = w1u + (size_t)e * IDIM * HDIM + (size_t)(nt * 64 + sr) * HDIM + sc;

  const int lane = tid & 63;
  const int wid = tid >> 6;
  const int wr = (wid >> 1) << 6;   // wave row 0/64
  const int wc = (wid & 1) << 5;    // wave col 0/32
  const int lr = lane & 15;
  const int lk = (lane >> 4) << 3;

  const int NTILES = HDIM / 32;  // 64

  uint4 a0X, a1X, a0Y, a1Y;
  float4 gLX, gHX, uLX, uHX, gLY, gHY, uLY, uHY;

  auto LOADS = [&](uint4& A0, uint4& A1, float4& GL, float4& GH,
                   float4& UL, float4& UH, int t) {
    if (t < NTILES) {
      const int k0 = t * 32;
      A0 = *(const uint4*)(aS0 + k0);
      A1 = *(const uint4*)(aS1 + k0);
      GL = *(const float4*)(gS + k0);
      GH = *(const float4*)(gS + k0 + 4);
      UL = *(const float4*)(uS + k0);
      UH = *(const float4*)(uS + k0 + 4);
    }
  };
  auto STORES = [&](const uint4& A0, const uint4& A1, const float4& GL,
                    const float4& GH, const float4& UL, const float4& UH, int b) {
    *(uint4*)&As[b][swz32(sr, sc)] = A0;
    *(uint4*)&As[b][swz32(sr + 64, sc)] = A1;
    uint4 t0;
    t0.x = pack2(GL.x, GL.y); t0.y = pack2(GL.z, GL.w);
    t0.z = pack2(GH.x, GH.y); t0.w = pack2(GH.z, GH.w);
    *(uint4*)&Bg[b][swz32(sr, sc)] = t0;
    t0.x = pack2(UL.x, UL.y); t0.y = pack2(UL.z, UL.w);
    t0.z = pack2(UH.x, UH.y); t0.w = pack2(UH.z, UH.w);
    *(uint4*)&Bu[b][swz32(sr, sc)] = t0;
  };

  f32x4 accG[4][2], accU[4][2];
#pragma unroll
  for (int i = 0; i < 4; ++i)
#pragma unroll
    for (int j = 0; j < 2; ++j) {
      accG[i][j] = (f32x4){0.f, 0.f, 0.f, 0.f};
      accU[i][j] = (f32x4){0.f, 0.f, 0.f, 0.f};
    }

  // Prologue: buf0 <- tile0; Y <- tile1 (older), X <- tile2 (newer).
  LOADS(a0X, a1X, gLX, gHX, uLX, uHX, 0);
  STORES(a0X, a1X, gLX, gHX, uLX, uHX, 0);   // implicit vmcnt drains tile0 only
  LOADS(a0Y, a1Y, gLY, gHY, uLY, uHY, 1);
  LOADS(a0X, a1X, gLX, gHX, uLX, uHX, 2);
  lds_barrier();

  for (int t = 0; t < NTILES; t += 2) {
    // ---- sub-iter A: compute tile t (buf0); stage tile t+1 from Y -> buf1.
    {
      bf16x8 af[4], bgf[2], buf_[2];
#pragma unroll
      for (int mi = 0; mi < 4; ++mi)
        af[mi] = *(const bf16x8*)&As[0][swz32(wr + mi * 16 + lr, lk)];
#pragma unroll
      for (int ni = 0; ni < 2; ++ni) {
        bgf[ni] = *(const bf16x8*)&Bg[0][swz32(wc + ni * 16 + lr, lk)];
        buf_[ni] = *(const bf16x8*)&Bu[0][swz32(wc + ni * 16 + lr, lk)];
      }
      STORES(a0Y, a1Y, gLY, gHY, uLY, uHY, 1);  // waits Y(t+1) loads only
      LOADS(a0Y, a1Y, gLY, gHY, uLY, uHY, t + 3);
      lds_barrier();
      __builtin_amdgcn_s_setprio(1);
#pragma unroll
      for (int mi = 0; mi < 4; ++mi)
#pragma unroll
        for (int ni = 0; ni < 2; ++ni) {
          accG[mi][ni] = __builtin_amdgcn_mfma_f32_16x16x32_bf16(af[mi], bgf[ni], accG[mi][ni], 0, 0, 0);
          accU[mi][ni] = __builtin_amdgcn_mfma_f32_16x16x32_bf16(af[mi], buf_[ni], accU[mi][ni], 0, 0, 0);
        }
      __builtin_amdgcn_s_setprio(0);
    }
    // ---- sub-iter B: compute tile t+1 (buf1); stage tile t+2 from X -> buf0.
    {
      bf16x8 af[4], bgf[2], buf_[2];
#pragma unroll
      for (int mi = 0; mi < 4; ++mi)
        af[mi] = *(const bf16x8*)&As[1][swz32(wr + mi * 16 + lr, lk)];
#pragma unroll
      for (int ni = 0; ni < 2; ++ni) {
        bgf[ni] = *(const bf16x8*)&Bg[1][swz32(wc + ni * 16 + lr, lk)];
        buf_[ni] = *(const bf16x8*)&Bu[1][swz32(wc + ni * 16 + lr, lk)];
      }
      if (t + 2 < NTILES) {
        STORES(a0X, a1X, gLX, gHX, uLX, uHX, 0);  // waits X(t+2) loads only
        LOADS(a0X, a1X, gLX, gHX, uLX, uHX, t + 4);
        lds_barrier();
      }
      __builtin_amdgcn_s_setprio(1);
#pragma unroll
      for (int mi = 0; mi < 4; ++mi)
#pragma unroll
        for (int ni = 0; ni < 2; ++ni) {
          accG[mi][ni] = __builtin_amdgcn_mfma_f32_16x16x32_bf16(af[mi], bgf[ni], accG[mi][ni], 0, 0, 0);
          accU[mi][ni] = __builtin_amdgcn_mfma_f32_16x16x32_bf16(af[mi], buf_[ni], accU[mi][ni], 0, 0, 0);
        }
      __builtin_amdgcn_s_setprio(0);
    }
  }

#pragma unroll
  for (int mi = 0; mi < 4; ++mi) {
#pragma unroll
    for (int ni = 0; ni < 2; ++ni) {
      const int col = nt * 64 + wc + ni * 16 + lr;
#pragma unroll
      for (int r = 0; r < 4; ++r) {
        const int mrow = mt * 128 + wr + mi * 16 + ((lane >> 4) << 2) + r;
        if (mrow < n_e) {
          const float gv = accG[mi][ni][r];
          const float uv = accU[mi][ni][r];
          const float hv = (gv / (1.f + __expf(-gv))) * uv;
          hbuf[(size_t)(rowbase + mrow) * IDIM + col] = bf1(hv);
        }
      }
    }
  }
}

// -------- GEMM2: po = h . w2^T (per expert). BM=128 BN=64 BK=32 -----------
__global__ __launch_bounds__(256, 2) void gemm2_kernel(
    const ushort* __restrict__ hbuf, const float* __restrict__ w2,
    const int* __restrict__ counts, const int* __restrict__ offsets,
    const int* __restrict__ nW2, const int* __restrict__ wl2,
    ushort* __restrict__ po)
{
  const int nTot = *nW2;
  const int L = (blockIdx.x & 7) * (MAXB2 / 8) + (blockIdx.x >> 3);
  if (L >= nTot) return;
  const int w = wl2[L];
  const int e = w >> 12, nt = (w >> 6) & 63, mt = w & 63;
  const int n_e = counts[e], rowbase = offsets[e];

  __shared__ ushort As[2][128 * 32];
  __shared__ ushort Bs[2][64 * 32];

  const int tid = threadIdx.x;
  const int sr = tid >> 2;
  const int sc = (tid & 3) << 3;
  const int r0 = mt * 128 + sr;
  const int r1 = r0 + 64;
  const int g0 = rowbase + (r0 < n_e ? r0 : n_e - 1);
  const int g1 = rowbase + (r1 < n_e ? r1 : n_e - 1);
  const ushort* aS0 = hbuf + (size_t)g0 * IDIM + sc;
  const ushort* aS1 = hbuf + (size_t)g1 * IDIM + sc;
  const float* bS = w2 + (size_t)e * HDIM * IDIM + (size_t)(nt * 64 + sr) * IDIM + sc;

  const int lane = tid & 63;
  const int wid = tid >> 6;
  const int wr = (wid >> 1) << 6;
  const int wc = (wid & 1) << 5;
  const int lr = lane & 15;
  const int lk = (lane >> 4) << 3;

  const int NTILES = IDIM / 32;  // 32

  uint4 a0X, a1X, a0Y, a1Y;
  float4 bLX, bHX, bLY, bHY;

  auto LOADS = [&](uint4& A0, uint4& A1, float4& BL, float4& BH, int t) {
    if (t < NTILES) {
      const int k0 = t * 32;
      A0 = *(const uint4*)(aS0 + k0);
      A1 = *(const uint4*)(aS1 + k0);
      BL = *(const float4*)(bS + k0);
      BH = *(const float4*)(bS + k0 + 4);
    }
  };
  auto STORES = [&](const uint4& A0, const uint4& A1, const float4& BL,
                    const float4& BH, int b) {
    *(uint4*)&As[b][swz32(sr, sc)] = A0;
    *(uint4*)&As[b][swz32(sr + 64, sc)] = A1;
    uint4 t0;
    t0.x = pack2(BL.x, BL.y); t0.y = pack2(BL.z, BL.w);
    t0.z = pack2(BH.x, BH.y); t0.w = pack2(BH.z, BH.w);
    *(uint4*)&Bs[b][swz32(sr, sc)] = t0;
  };

  f32x4 acc[4][2];
#pragma unroll
  for (int i = 0; i < 4; ++i)
#pragma unroll
    for (int j = 0; j < 2; ++j) acc[i][j] = (f32x4){0.f, 0.f, 0.f, 0.f};

  LOADS(a0X, a1X, bLX, bHX, 0);
  STORES(a0X, a1X, bLX, bHX, 0);
  LOADS(a0Y, a1Y, bLY, bHY, 1);
  LOADS(a0X, a1X, bLX, bHX, 2);
  lds_barrier();

  for (int t = 0; t < NTILES; t += 2) {
    {
      bf16x8 af[4], bf[2];
#pragma unroll
      for (int mi = 0; mi < 4; ++mi)
        af[mi] = *(const bf16x8*)&As[0][swz32(wr + mi * 16 + lr, lk)];
#pragma unroll
      for (int ni = 0; ni < 2; ++ni)
        bf[ni] = *(const bf16x8*)&Bs[0][swz32(wc + ni * 16 + lr, lk)];
      STORES(a0Y, a1Y, bLY, bHY, 1);
      LOADS(a0Y, a1Y, bLY, bHY, t + 3);
      lds_barrier();
      __builtin_amdgcn_s_setprio(1);
#pragma unroll
      for (int mi = 0; mi < 4; ++mi)
#pragma unroll
        for (int ni = 0; ni < 2; ++ni)
          acc[mi][ni] = __builtin_amdgcn_mfma_f32_16x16x32_bf16(af[mi], bf[ni], acc[mi][ni], 0, 0, 0);
      __builtin_amdgcn_s_setprio(0);
    }
    {
      bf16x8 af[4], bf[2];
#pragma unroll
      for (int mi = 0; mi < 4; ++mi)
        af[mi] = *(const bf16x8*)&As[1][swz32(wr + mi * 16 + lr, lk)];
#pragma unroll
      for (int ni = 0; ni < 2; ++ni)
        bf[ni] = *(const bf16x8*)&Bs[1][swz32(wc + ni * 16 + lr, lk)];
      if (t + 2 < NTILES) {
        STORES(a0X, a1X, bLX, bHX, 0);
        LOADS(a0X, a1X, bLX, bHX, t + 4);
        lds_barrier();
      }
      __builtin_amdgcn_s_setprio(1);
#pragma unroll
      for (int mi = 0; mi < 4; ++mi)
#pragma unroll
        for (int ni = 0; ni < 2; ++ni)
          acc[mi][ni] = __builtin_amdgcn_mfma_f32_16x16x32_bf16(af[mi], bf[ni], acc[mi][ni], 0, 0, 0);
      __builtin_amdgcn_s_setprio(0);
    }
  }

#pragma unroll
  for (int mi = 0; mi < 4; ++mi) {
#pragma unroll
    for (int ni = 0; ni < 2; ++ni) {
      const int col = nt * 64 + wc + ni * 16 + lr;
#pragma unroll
      for (int r = 0; r < 4; ++r) {
        const int mrow = mt * 128 + wr + mi * 16 + ((lane >> 4) << 2) + r;
        if (mrow < n_e)
          po[(size_t)(rowbase + mrow) * HDIM + col] = bf1(acc[mi][ni][r]);
      }
    }
  }
}

// ---------------- combine: out[t] = sum_k w_k * po[row_k] -----------------
__global__ __launch_bounds__(256) void combine_kernel(
    const ushort* __restrict__ po, const int* __restrict__ inv,
    const float* __restrict__ tw, float* __restrict__ out)
{
  const int t = blockIdx.x;
  const int r0 = inv[t * 4 + 0], r1 = inv[t * 4 + 1];
  const int r2 = inv[t * 4 + 2], r3 = inv[t * 4 + 3];
  const float w0 = tw[t * 4 + 0], w1 = tw[t * 4 + 1];
  const float w2v = tw[t * 4 + 2], w3 = tw[t * 4 + 3];
  const int i = threadIdx.x;  // HDIM/8 == 256 lanes, 8 elems each
  uint4 v0 = *(const uint4*)(po + (size_t)r0 * HDIM + i * 8);
  uint4 v1 = *(const uint4*)(po + (size_t)r1 * HDIM + i * 8);
  uint4 v2 = *(const uint4*)(po + (size_t)r2 * HDIM + i * 8);
  uint4 v3 = *(const uint4*)(po + (size_t)r3 * HDIM + i * 8);
  float o[8];
#pragma unroll
  for (int w = 0; w < 4; ++w) {
    const uint32_t a = (&v0.x)[w], b = (&v1.x)[w], c = (&v2.x)[w], d = (&v3.x)[w];
    o[w * 2 + 0] = w0 * __builtin_bit_cast(float, a << 16) +
                   w1 * __builtin_bit_cast(float, b << 16) +
                   w2v * __builtin_bit_cast(float, c << 16) +
                   w3 * __builtin_bit_cast(float, d << 16);
    o[w * 2 + 1] = w0 * __builtin_bit_cast(float, a & 0xffff0000u) +
                   w1 * __builtin_bit_cast(float, b & 0xffff0000u) +
                   w2v * __builtin_bit_cast(float, c & 0xffff0000u) +
                   w3 * __builtin_bit_cast(float, d & 0xffff0000u);
  }
  float4* o4 = (float4*)(out + (size_t)t * HDIM + i * 8);
  o4[0] = (float4){o[0], o[1], o[2], o[3]};
  o4[1] = (float4){o[4], o[5], o[6], o[7]};
}

extern "C" void kernel_launch(void* const* d_in, const int* in_sizes, int n_in,
                              void* d_out, int out_size, void* d_ws, size_t ws_size,
                              hipStream_t stream) {
  const float* x   = (const float*)d_in[0];
  const float* gw  = (const float*)d_in[1];
  const float* w1g = (const float*)d_in[2];
  const float* w1u = (const float*)d_in[3];
  const float* w2  = (const float*)d_in[4];
  float* out = (float*)d_out;

  char* ws = (char*)d_ws;
  ushort* xb     = (ushort*)(ws + 0);
  ushort* hbuf   = (ushort*)(ws + 8388608);
  ushort* po     = (ushort*)(ws + 25165824);
  int*    tkid   = (int*)   (ws + 58720256);
  float*  tkw    = (float*) (ws + 58753024);
  int*    rowTok = (int*)   (ws + 58785792);
  int*    inv    = (int*)   (ws + 58818560);
  int*    ctrl   = (int*)   (ws + 58851328);
  int* counts  = ctrl;          // 16
  int* cursors = ctrl + 16;     // 16
  int* offsets = ctrl + 32;     // 17
  int* nW1     = ctrl + 50;     // 1
  int* nW2     = ctrl + 51;     // 1
  int* wl1     = ctrl + 64;     // MAXB1 (1280)
  int* wl2     = ctrl + 64 + MAXB1;  // MAXB2 (2560)

  (void)hipMemsetAsync(ctrl, 0, 256, stream);
  router_kernel<<<TTOK / 4, 256, 0, stream>>>(x, gw, xb, tkid, tkw, counts);
  plan_kernel<<<1, 64, 0, stream>>>(counts, offsets, nW1, nW2, wl1, wl2);
  scatter_kernel<<<TTOK / 256, 256, 0, stream>>>(tkid, offsets, cursors, rowTok, inv);
  gemm1_kernel<<<MAXB1, 256, 0, stream>>>(xb, w1g, w1u, rowTok, counts, offsets,
                                          nW1, wl1, hbuf);
  gemm2_kernel<<<MAXB2, 256, 0, stream>>>(hbuf, w2, counts, offsets,
                                          nW2, wl2, po);
  combine_kernel<<<TTOK, 256, 0, stream>>>(po, inv, tkw, out);
}